// Round 16
// baseline (787.501 us; speedup 1.0000x reference)
//
#include <hip/hip_runtime.h>

typedef __bf16 bf16;
typedef __bf16 bf16x8 __attribute__((ext_vector_type(8)));
typedef float f32x4 __attribute__((ext_vector_type(4)));

#define L_TOT 110592   // 48^3
#define TOKS  221184   // 2*L
#define NWIN  3456     // 2*12^3

static __device__ __forceinline__ f32x4 mfma16(bf16x8 a, bf16x8 b, f32x4 c) {
    return __builtin_amdgcn_mfma_f32_16x16x32_bf16(a, b, c, 0, 0, 0);
}
static __device__ __forceinline__ bf16x8 ld8(const bf16* p) { return *(const bf16x8*)p; }

// ---------------- setup kernels ----------------
// fragment-major: dst[(((n>>6)*(K/32) + (k>>5))*64 + (n&63))*32 + (k&31)] = src[k][n]
__global__ void wt_frag(const float* __restrict__ src, bf16* __restrict__ dst, int K, int N) {
    int i = blockIdx.x * 256 + threadIdx.x;
    if (i >= K * N) return;
    int kw = i & 31, col = (i >> 5) & 63, rest = i >> 11;
    int nks = K >> 5;
    int ks = rest % nks, chunk = rest / nks;
    int n = chunk * 64 + col, k = ks * 32 + kw;
    dst[i] = (bf16)src[k * N + n];
}

__global__ void bias6_build(const float* __restrict__ rpb, float* __restrict__ bias6) {
    int i = blockIdx.x * 256 + threadIdx.x;
    if (i >= 6 * 64 * 64) return;
    int h = i >> 12, n = (i >> 6) & 63, m = i & 63;
    int r0 = (n >> 4) - (m >> 4) + 3;
    int r1 = ((n >> 2) & 3) - ((m >> 2) & 3) + 3;
    int r2 = (n & 3) - (m & 3) + 3;
    bias6[i] = rpb[(r0 * 49 + r1 * 7 + r2) * 6 + h];
}

// ---------------- LN1 (wave per token; fragment-major output) ----------------
__global__ void ln1_window(const float* __restrict__ x, const float* __restrict__ g,
                           const float* __restrict__ bt, bf16* __restrict__ xw) {
    int wave = threadIdx.x >> 6, lane = threadIdx.x & 63;
    int t = blockIdx.x * 4 + wave;
    const float* row = x + (long)t * 192;
    float v0 = row[lane], v1 = row[lane + 64], v2 = row[lane + 128];
    float s = v0 + v1 + v2;
    #pragma unroll
    for (int m = 1; m < 64; m <<= 1) s += __shfl_xor(s, m);
    float mu = s * (1.0f / 192.0f);
    float d0 = v0 - mu, d1 = v1 - mu, d2 = v2 - mu;
    float q = d0 * d0 + d1 * d1 + d2 * d2;
    #pragma unroll
    for (int m = 1; m < 64; m <<= 1) q += __shfl_xor(q, m);
    float r = rsqrtf(q * (1.0f / 192.0f) + 1e-5f);
    int b = t / L_TOT, l = t - b * L_TOT;
    int dz = l / 2304, rem = l - dz * 2304;
    int hy = rem / 48, wx = rem - hy * 48;
    int w = ((b * 12 + (dz >> 2)) * 12 + (hy >> 2)) * 12 + (wx >> 2);
    int n = (dz & 3) * 16 + (hy & 3) * 4 + (wx & 3);
    bf16* o = xw + (long)w * 12288 + (lane >> 5) * 2048 + n * 32 + (lane & 31);
    o[0]    = (bf16)(d0 * r * g[lane]       + bt[lane]);
    o[4096] = (bf16)(d1 * r * g[lane + 64]  + bt[lane + 64]);
    o[8192] = (bf16)(d2 * r * g[lane + 128] + bt[lane + 128]);
}

// ---------------- QKV GEMM: fragment-major A/B, coalesced fragment loads ----------------
__global__ __launch_bounds__(256) void gemm_qkv(
    const bf16* __restrict__ xw, const bf16* __restrict__ wt,
    const float* __restrict__ bqkv,
    bf16* __restrict__ qb, bf16* __restrict__ kb_, bf16* __restrict__ vtb) {
    int m0 = blockIdx.x * 128;
    int w0 = m0 >> 6;
    int wid = threadIdx.x >> 6, lane = threadIdx.x & 63;
    int wr = wid >> 1, wc = wid & 1;
    int lo = lane & 15, hi = lane >> 4;
    f32x4 zf = {0.f, 0.f, 0.f, 0.f};

    const bf16* Ab = xw + (long)(w0 + wr) * 12288 + (lo * 32 + hi * 8);
    bf16x8 a[4][6];
    #pragma unroll
    for (int ti = 0; ti < 4; ++ti)
        #pragma unroll
        for (int ks = 0; ks < 6; ++ks)
            a[ti][ks] = ld8(Ab + ks * 2048 + ti * 512);

    #pragma unroll
    for (int nc = 0; nc < 9; ++nc) {
        int sect = nc / 3;              // 0=q 1=k 2=v
        int cb0 = (nc - sect * 3) * 64;
        f32x4 acc[4][2];
        #pragma unroll
        for (int i = 0; i < 4; ++i) { acc[i][0] = zf; acc[i][1] = zf; }
        const bf16* Bb = wt + (long)nc * 12288 + (wc * 32 + lo) * 32 + hi * 8;
        #pragma unroll
        for (int ks = 0; ks < 6; ++ks) {
            bf16x8 b0 = ld8(Bb + ks * 2048);
            bf16x8 b1 = ld8(Bb + ks * 2048 + 512);
            #pragma unroll
            for (int ti = 0; ti < 4; ++ti) {
                acc[ti][0] = mfma16(a[ti][ks], b0, acc[ti][0]);
                acc[ti][1] = mfma16(a[ti][ks], b1, acc[ti][1]);
            }
        }
        #pragma unroll
        for (int ti = 0; ti < 4; ++ti)
            #pragma unroll
            for (int j = 0; j < 4; ++j) {
                int trow = m0 + wr * 64 + ti * 16 + hi * 4 + j;
                int w = trow >> 6, n = trow & 63;
                #pragma unroll
                for (int tj = 0; tj < 2; ++tj) {
                    int cw = cb0 + wc * 32 + tj * 16 + lo;   // 0..191 within section
                    int h = cw >> 5, d = cw & 31;
                    float val = acc[ti][tj][j] + bqkv[sect * 192 + cw];
                    long wh = (long)(w * 6 + h);
                    if (sect == 0)       qb[(wh * 64 + n) * 32 + d] = (bf16)(val * 0.17677669529663687f);
                    else if (sect == 1)  kb_[(wh * 64 + n) * 32 + d] = (bf16)val;
                    else                 vtb[(wh * 32 + d) * 64 + n] = (bf16)val;
                }
            }
    }
}

// ---------------- light attention: block=window, wave=head, no barriers ----------------
__global__ __launch_bounds__(384) void attn_light(
    const bf16* __restrict__ qb, const bf16* __restrict__ kb_,
    const bf16* __restrict__ vtb, const float* __restrict__ bias6,
    bf16* __restrict__ aw) {
    __shared__ char p_smem[6 * 8192];   // per head: [64][64] bf16 XOR-swizzled
    int w = blockIdx.x;
    int h = threadIdx.x >> 6;
    int lane = threadIdx.x & 63;
    int lo = lane & 15, hi = lane >> 4;
    char* ph = p_smem + h * 8192;
    long wh = (long)(w * 6 + h);
    f32x4 zf = {0.f, 0.f, 0.f, 0.f};

    bf16x8 qa[4], kb[4];
    #pragma unroll
    for (int ti = 0; ti < 4; ++ti) qa[ti] = ld8(qb  + (wh * 64 + ti * 16 + lo) * 32 + hi * 8);
    #pragma unroll
    for (int tj = 0; tj < 4; ++tj) kb[tj] = ld8(kb_ + (wh * 64 + tj * 16 + lo) * 32 + hi * 8);
    f32x4 s[4][4];
    #pragma unroll
    for (int ti = 0; ti < 4; ++ti)
        #pragma unroll
        for (int tj = 0; tj < 4; ++tj)
            s[ti][tj] = mfma16(qa[ti], kb[tj], zf);

    const float* bh = bias6 + h * 4096;
    #pragma unroll
    for (int ti = 0; ti < 4; ++ti)
        #pragma unroll
        for (int j = 0; j < 4; ++j) {
            int rr = ti * 16 + hi * 4 + j;
            float ev[4];
            #pragma unroll
            for (int tj = 0; tj < 4; ++tj) s[ti][tj][j] += bh[rr * 64 + tj * 16 + lo];
            float mx = fmaxf(fmaxf(s[ti][0][j], s[ti][1][j]), fmaxf(s[ti][2][j], s[ti][3][j]));
            #pragma unroll
            for (int m = 1; m < 16; m <<= 1) mx = fmaxf(mx, __shfl_xor(mx, m));
            float sum = 0.f;
            #pragma unroll
            for (int tj = 0; tj < 4; ++tj) { ev[tj] = __expf(s[ti][tj][j] - mx); sum += ev[tj]; }
            #pragma unroll
            for (int m = 1; m < 16; m <<= 1) sum += __shfl_xor(sum, m);
            float inv = 1.0f / sum;
            #pragma unroll
            for (int tj = 0; tj < 4; ++tj) {
                int byte = ((rr * 64 + tj * 16 + lo) * 2) ^ ((rr & 7) << 4);
                *(bf16*)(ph + byte) = (bf16)(ev[tj] * inv);
            }
        }

    f32x4 o[4][2];
    #pragma unroll
    for (int i = 0; i < 4; ++i) { o[i][0] = zf; o[i][1] = zf; }
    #pragma unroll
    for (int ks2 = 0; ks2 < 2; ++ks2) {
        bf16x8 pa[4], vb[2];
        #pragma unroll
        for (int ti = 0; ti < 4; ++ti) {
            int row = ti * 16 + lo;
            pa[ti] = *(const bf16x8*)(ph + ((row * 128 + ks2 * 64 + hi * 16) ^ ((row & 7) << 4)));
        }
        #pragma unroll
        for (int td = 0; td < 2; ++td)
            vb[td] = ld8(vtb + (wh * 32 + td * 16 + lo) * 64 + ks2 * 32 + hi * 8);
        #pragma unroll
        for (int ti = 0; ti < 4; ++ti)
            #pragma unroll
            for (int td = 0; td < 2; ++td)
                o[ti][td] = mfma16(pa[ti], vb[td], o[ti][td]);
    }
    // fragment-major aw: [w][h][n][32]
    bf16* orow = aw + wh * 2048;
    #pragma unroll
    for (int ti = 0; ti < 4; ++ti)
        #pragma unroll
        for (int td = 0; td < 2; ++td)
            #pragma unroll
            for (int j = 0; j < 4; ++j)
                orow[(ti * 16 + hi * 4 + j) * 32 + td * 16 + lo] = (bf16)o[ti][td][j];
}

// ---------------- proj GEMM + fused LN2: M=64/block, 4 waves split N, dual epilogue ----------------
__global__ __launch_bounds__(256) void gemm_proj_ln(
    const bf16* __restrict__ aw, const bf16* __restrict__ wt,
    const float* __restrict__ bias, const float* __restrict__ x,
    const float* __restrict__ g2, const float* __restrict__ b2,
    bf16* __restrict__ out1, bf16* __restrict__ y) {
    __shared__ float sred[64][4][2];
    int w0 = blockIdx.x;                  // window id (0..NWIN-1)
    int wc = threadIdx.x >> 6, lane = threadIdx.x & 63;
    int lo = lane & 15, hi = lane >> 4;
    f32x4 zf = {0.f, 0.f, 0.f, 0.f};
    f32x4 acc[3][4];                      // [tj][ti]
    #pragma unroll
    for (int tj = 0; tj < 3; ++tj)
        #pragma unroll
        for (int ti = 0; ti < 4; ++ti) acc[tj][ti] = zf;

    const bf16* Ab = aw + (long)w0 * 12288 + lo * 32 + hi * 8;
    #pragma unroll
    for (int ks = 0; ks < 6; ++ks) {
        bf16x8 a[4];
        #pragma unroll
        for (int ti = 0; ti < 4; ++ti) a[ti] = ld8(Ab + ks * 2048 + ti * 512);
        #pragma unroll
        for (int tj = 0; tj < 3; ++tj) {
            int col0 = wc * 48 + tj * 16;
            bf16x8 b0 = ld8(wt + ((long)((col0 >> 6) * 6 + ks) * 64 + (col0 & 63) + lo) * 32 + hi * 8);
            #pragma unroll
            for (int ti = 0; ti < 4; ++ti)
                acc[tj][ti] = mfma16(a[ti], b0, acc[tj][ti]);
        }
    }

    // unwindow indices (uniform part)
    int bb = w0 / 1728; int remw = w0 - bb * 1728;
    int dq = remw / 144; int rem2 = remw - dq * 144;
    int hq = rem2 / 12; int wq = rem2 - hq * 12;

    // residual add + per-row partial stats (rows rr = ti*16 + hi*4 + j)
    int lcache[4][4];
    float sum[4][4], sq[4][4];
    #pragma unroll
    for (int ti = 0; ti < 4; ++ti)
        #pragma unroll
        for (int j = 0; j < 4; ++j) {
            int n = ti * 16 + hi * 4 + j;
            int l = (dq * 4 + (n >> 4)) * 2304 + (hq * 4 + ((n >> 2) & 3)) * 48 + (wq * 4 + (n & 3));
            lcache[ti][j] = l;
            long xbase = ((long)bb * L_TOT + l) * 192;
            float s = 0.f, q = 0.f;
            #pragma unroll
            for (int tj = 0; tj < 3; ++tj) {
                int col = wc * 48 + tj * 16 + lo;
                float v = x[xbase + col] + acc[tj][ti][j] + bias[col];
                acc[tj][ti][j] = v;
                s += v; q = fmaf(v, v, q);
            }
            #pragma unroll
            for (int m = 1; m < 16; m <<= 1) { s += __shfl_xor(s, m); q += __shfl_xor(q, m); }
            sum[ti][j] = s; sq[ti][j] = q;
        }
    if (lo == 0) {
        #pragma unroll
        for (int ti = 0; ti < 4; ++ti)
            #pragma unroll
            for (int j = 0; j < 4; ++j) {
                int rr = ti * 16 + hi * 4 + j;
                sred[rr][wc][0] = sum[ti][j];
                sred[rr][wc][1] = sq[ti][j];
            }
    }
    __syncthreads();

    #pragma unroll
    for (int ti = 0; ti < 4; ++ti)
        #pragma unroll
        for (int j = 0; j < 4; ++j) {
            int rr = ti * 16 + hi * 4 + j;
            float S = sred[rr][0][0] + sred[rr][1][0] + sred[rr][2][0] + sred[rr][3][0];
            float Q = sred[rr][0][1] + sred[rr][1][1] + sred[rr][2][1] + sred[rr][3][1];
            float mu = S * (1.0f / 192.0f);
            float var = Q * (1.0f / 192.0f) - mu * mu;
            float r = rsqrtf(var + 1e-5f);
            long t = (long)bb * L_TOT + lcache[ti][j];
            long fb = (t >> 6) * 12288 + (t & 63) * 32;
            #pragma unroll
            for (int tj = 0; tj < 3; ++tj) {
                int col0 = wc * 48 + tj * 16;
                int col = col0 + lo;
                float v = acc[tj][ti][j];
                long idx = fb + (col0 >> 5) * 2048 + (col0 & 31) + lo;
                out1[idx] = (bf16)v;
                y[idx]    = (bf16)((v - mu) * r * g2[col] + b2[col]);
            }
        }
}

// ---------------- fc1 GEMM: fragment-major A/B, transpose epilogue (unfused) ----------------
__global__ __launch_bounds__(256) void gemm_fc1(
    const bf16* __restrict__ y, const bf16* __restrict__ wt,
    const float* __restrict__ bias, bf16* __restrict__ h_t) {
    __shared__ bf16 tl[64][136];
    int m0 = blockIdx.x * 128;
    int c0 = m0 >> 6;
    int wid = threadIdx.x >> 6, lane = threadIdx.x & 63;
    int wr = wid >> 1, wc = wid & 1;
    int lo = lane & 15, hi = lane >> 4;
    f32x4 zf = {0.f, 0.f, 0.f, 0.f};
    int bb = m0 / L_TOT; int l0 = m0 - bb * L_TOT;
    int col = threadIdx.x >> 2, seg = threadIdx.x & 3;

    const bf16* Ab = y + (long)(c0 + wr) * 12288 + (lo * 32 + hi * 8);
    bf16x8 a[4][6];
    #pragma unroll
    for (int ti = 0; ti < 4; ++ti)
        #pragma unroll
        for (int ks = 0; ks < 6; ++ks)
            a[ti][ks] = ld8(Ab + ks * 2048 + ti * 512);

    #pragma unroll
    for (int nc = 0; nc < 6; ++nc) {
        f32x4 acc[4][2];
        #pragma unroll
        for (int i = 0; i < 4; ++i) { acc[i][0] = zf; acc[i][1] = zf; }
        const bf16* Bb = wt + (long)nc * 12288 + (wc * 32 + lo) * 32 + hi * 8;
        #pragma unroll
        for (int ks = 0; ks < 6; ++ks) {
            bf16x8 b0 = ld8(Bb + ks * 2048);
            bf16x8 b1 = ld8(Bb + ks * 2048 + 512);
            #pragma unroll
            for (int ti = 0; ti < 4; ++ti) {
                acc[ti][0] = mfma16(a[ti][ks], b0, acc[ti][0]);
                acc[ti][1] = mfma16(a[ti][ks], b1, acc[ti][1]);
            }
        }
        if (nc) __syncthreads();
        #pragma unroll
        for (int ti = 0; ti < 4; ++ti)
            #pragma unroll
            for (int tj = 0; tj < 2; ++tj)
                #pragma unroll
                for (int j = 0; j < 4; ++j) {
                    int rl = wr * 64 + ti * 16 + hi * 4 + j;
                    int cl = wc * 32 + tj * 16 + lo;
                    tl[cl][rl] = (bf16)(acc[ti][tj][j] + bias[nc * 64 + cl]);
                }
        __syncthreads();
        bf16* dst = h_t + ((long)bb * 384 + nc * 64 + col) * L_TOT + l0 + seg * 32;
        #pragma unroll
        for (int i8 = 0; i8 < 4; ++i8)
            *(bf16x8*)(dst + i8 * 8) = *(const bf16x8*)(&tl[col][seg * 32 + i8 * 8]);
    }
}

// ---------------- depthwise conv 3^3 + BN + GELU (slab=4, stride-56 LDS, division-free staging) ----------------
__global__ __launch_bounds__(320) void dwconv_bn_gelu(
    const bf16* __restrict__ h_t, const float* __restrict__ wconv,
    const float* __restrict__ cb, const float* __restrict__ bng,
    const float* __restrict__ bnb, const float* __restrict__ bnm,
    const float* __restrict__ bnv, bf16* __restrict__ g_t) {
    // 1 guard row + 6*48 data rows, stride 56; cols 48..55 of every row are zero. 32368B -> 5 blocks/CU.
    __shared__ __align__(16) bf16 tile[289 * 56];
    int blk = blockIdx.x;
    int bb = blk / 4608; int rem = blk - bb * 4608;
    int ch = rem / 12; int zb = rem - ch * 12; int z0 = zb * 4;
    const bf16* src = h_t + ((long)bb * 384 + ch) * L_TOT;

    int y = threadIdx.x / 6, cx = threadIdx.x - y * 6, x0 = cx * 8;
    bool active = threadIdx.x < 288;

    // zero guard cells: guard row (7 uint4) + right columns (48..55) of 288 data rows
    uint4 zv = make_uint4(0u, 0u, 0u, 0u);
    for (int i = threadIdx.x; i < 295; i += 320) {
        int e = (i < 7) ? i * 8 : ((i - 7 + 1) * 56 + 48);
        *(uint4*)(tile + e) = zv;
    }
    // stage 6 planes x 48 rows x 48 cols, division-free (thread's own (y,cx)), 16B-aligned writes
    if (active) {
        #pragma unroll
        for (int zi = 0; zi < 6; ++zi) {
            int gz = z0 - 1 + zi;
            uint4 val = zv;
            if (gz >= 0 && gz < 48) val = *(const uint4*)(src + (long)gz * 2304 + y * 48 + x0);
            *(uint4*)(tile + (1 + zi * 48 + y) * 56 + x0) = val;
        }
    }
    float wgt[27];
    #pragma unroll
    for (int i = 0; i < 27; ++i) wgt[i] = wconv[ch * 27 + i];
    float scale = bng[ch] * rsqrtf(bnv[ch] + 1e-5f);
    float shift = bnb[ch] - bnm[ch] * scale;
    float cbias = cb[ch];
    __syncthreads();

    if (active) {
        __builtin_assume(y < 48);
        bool up_ok = (y > 0), dn_ok = (y < 47);
        bf16* dstc = g_t + ((long)bb * 384 + ch) * L_TOT + (long)z0 * 2304 + y * 48 + x0;
        float acc[4][8];
        #pragma unroll
        for (int p = 0; p < 4; ++p)
            #pragma unroll
            for (int k = 0; k < 8; ++k) acc[p][k] = 0.f;

        #pragma unroll
        for (int zi = 0; zi < 6; ++zi) {
            const bf16* plane = tile + (1 + zi * 48) * 56;
            #pragma unroll
            for (int dy = 0; dy < 3; ++dy) {
                bool ok = (dy == 1) || (dy == 0 ? up_ok : dn_ok);
                if (ok) {
                    const bf16* rp = plane + (y + dy - 1) * 56 + x0;
                    bf16x8 mv = ld8(rp);            // single ds_read_b128 (16B aligned)
                    float s[10];
                    s[0] = (float)rp[-1];           // cx==0 -> prev row col 55 == 0
                    #pragma unroll
                    for (int i = 0; i < 8; ++i) s[i + 1] = (float)mv[i];
                    s[9] = (float)rp[8];            // cx==5 -> col 48 == 0
                    #pragma unroll
                    for (int dz = 0; dz < 3; ++dz) {
                        int p = zi - dz;
                        if (p >= 0 && p <= 3) {     // compile-time after unroll
                            float w0 = wgt[dz * 9 + dy * 3 + 0];
                            float w1 = wgt[dz * 9 + dy * 3 + 1];
                            float w2 = wgt[dz * 9 + dy * 3 + 2];
                            #pragma unroll
                            for (int k = 0; k < 8; ++k)
                                acc[p][k] = fmaf(w0, s[k], fmaf(w1, s[k + 1], fmaf(w2, s[k + 2], acc[p][k])));
                        }
                    }
                }
            }
            if (zi >= 2) {
                int p = zi - 2;
                bf16x8 ov;
                #pragma unroll
                for (int k = 0; k < 8; ++k) {
                    float v = acc[p][k] + cbias;
                    v = fmaf(v, scale, shift);
                    // GELU tanh form via exp2 (log2e folded): v - v/(2^(u2) + 1)
                    float v2 = v * v;
                    float u2 = v * fmaf(v2, 0.10294357f, 2.3022080918f);
                    float e  = exp2f(u2);
                    float q  = __builtin_amdgcn_rcpf(e + 1.0f);
                    ov[k] = (bf16)(v - v * q);
                }
                *(bf16x8*)(dstc + p * 2304) = ov;
            }
        }
    }
}

// ---------------- fc2 GEMM: M=64, 2-deep prefetch, early residual preload (frag-major out1) ----------------
__global__ __launch_bounds__(256) void gemm_fc2(
    const bf16* __restrict__ g_t, const bf16* __restrict__ wt,
    const float* __restrict__ bias, const bf16* __restrict__ out1,
    float* __restrict__ out) {
    __shared__ bf16 As[2][4096];        // [64 tok][64 ch], elem = tok*64 + (ch ^ (S(tok)<<3))
    int m0 = blockIdx.x * 64;
    int wc = threadIdx.x >> 6, lane = threadIdx.x & 63;
    int lo = lane & 15, hi = lane >> 4;
    int bb = m0 / L_TOT, l0 = m0 - bb * L_TOT;
    f32x4 zf = {0.f, 0.f, 0.f, 0.f};
    f32x4 acc[3][4];                    // [tj][ti]
    #pragma unroll
    for (int tj = 0; tj < 3; ++tj)
        #pragma unroll
        for (int ti = 0; ti < 4; ++ti) acc[tj][ti] = zf;

    int sch = threadIdx.x >> 3;          // channel within pass (0..31)
    int seg = threadIdx.x & 7;           // 8-token segment
    const bf16* srcb = g_t + ((long)bb * 384 + sch) * L_TOT + l0 + seg * 8;

    bf16x8 r[2][2];
    // tile 0 -> As[0]
    #pragma unroll
    for (int p = 0; p < 2; ++p) r[0][p] = ld8(srcb + (long)(p * 32) * L_TOT);
    #pragma unroll
    for (int p = 0; p < 2; ++p)
        #pragma unroll
        for (int i = 0; i < 8; ++i)
            As[0][(seg * 8 + i) * 64 + ((p * 32 + sch) ^ (((seg ^ i) & 7) << 3))] = r[0][p][i];
    // 2-deep prefetch: tiles 1 and 2
    #pragma unroll
    for (int p = 0; p < 2; ++p) r[0][p] = ld8(srcb + (long)(64 + p * 32) * L_TOT);
    #pragma unroll
    for (int p = 0; p < 2; ++p) r[1][p] = ld8(srcb + (long)(128 + p * 32) * L_TOT);

    // early residual preload from fragment-major out1 (overlaps the whole GEMM)
    long fbase = (long)(m0 >> 6) * 12288;
    float res[3][4][4];
    #pragma unroll
    for (int tj = 0; tj < 3; ++tj)
        #pragma unroll
        for (int ti = 0; ti < 4; ++ti)
            #pragma unroll
            for (int j = 0; j < 4; ++j) {
                int trow6 = ti * 16 + hi * 4 + j;
                int c = wc * 48 + tj * 16 + lo;
                res[tj][ti][j] = (float)out1[fbase + (c >> 5) * 2048 + trow6 * 32 + (c & 31)];
            }
    __syncthreads();

    #pragma unroll
    for (int t = 0; t < 6; ++t) {
        const bf16* Ac = As[t & 1];
        #pragma unroll
        for (int ksin = 0; ksin < 2; ++ksin) {
            bf16x8 a[4];
            #pragma unroll
            for (int ti = 0; ti < 4; ++ti) {
                int rr = ti * 16 + lo;
                int S = ((rr >> 3) ^ rr) & 7;
                a[ti] = *(const bf16x8*)&Ac[rr * 64 + ((ksin * 32 + hi * 8) ^ (S << 3))];
            }
            #pragma unroll
            for (int tj = 0; tj < 3; ++tj) {
                int cstart = wc * 48 + tj * 16;
                bf16x8 b0 = ld8(wt + ((long)((cstart >> 6) * 12 + t * 2 + ksin) * 64 + (cstart & 63) + lo) * 32 + hi * 8);
                #pragma unroll
                for (int ti = 0; ti < 4; ++ti)
                    acc[tj][ti] = mfma16(a[ti], b0, acc[tj][ti]);
            }
        }
        if (t < 5) {
            bf16* An = As[(t + 1) & 1];
            #pragma unroll
            for (int p = 0; p < 2; ++p)
                #pragma unroll
                for (int i = 0; i < 8; ++i)
                    An[(seg * 8 + i) * 64 + ((p * 32 + sch) ^ (((seg ^ i) & 7) << 3))] = r[t & 1][p][i];
        }
        if (t < 3) {
            #pragma unroll
            for (int p = 0; p < 2; ++p)
                r[t & 1][p] = ld8(srcb + (long)((t + 3) * 64 + p * 32) * L_TOT);
        }
        __syncthreads();
    }
    #pragma unroll
    for (int tj = 0; tj < 3; ++tj)
        #pragma unroll
        for (int ti = 0; ti < 4; ++ti)
            #pragma unroll
            for (int j = 0; j < 4; ++j) {
                long trow = m0 + ti * 16 + hi * 4 + j;
                int col = wc * 48 + tj * 16 + lo;
                out[trow * 192 + col] = res[tj][ti][j] + acc[tj][ti][j] + bias[col];
            }
}

// ---------------- host ----------------
extern "C" void kernel_launch(void* const* d_in, const int* in_sizes, int n_in,
                              void* d_out, int out_size, void* d_ws, size_t ws_size,
                              hipStream_t stream) {
    (void)in_sizes; (void)n_in; (void)out_size; (void)ws_size;
    const float* x     = (const float*)d_in[0];
    const float* ln1g  = (const float*)d_in[4];
    const float* ln1b  = (const float*)d_in[5];
    const float* ln2g  = (const float*)d_in[6];
    const float* ln2b  = (const float*)d_in[7];
    const float* qkvw  = (const float*)d_in[8];
    const float* qkvb  = (const float*)d_in[9];
    const float* rpb   = (const float*)d_in[10];
    const float* projw = (const float*)d_in[11];
    const float* projb = (const float*)d_in[12];
    const float* fc1w  = (const float*)d_in[13];
    const float* fc1b  = (const float*)d_in[14];
    const float* dww   = (const float*)d_in[15];
    const float* dwb   = (const float*)d_in[16];
    const float* bng   = (const float*)d_in[17];
    const float* bnb   = (const float*)d_in[18];
    const float* bnm   = (const float*)d_in[19];
    const float* bnv   = (const float*)d_in[20];
    const float* fc2w  = (const float*)d_in[21];
    const float* fc2b  = (const float*)d_in[22];
    float* out = (float*)d_out;

    char* ws = (char*)d_ws;
    size_t o = 0;
    bf16*  out1 = (bf16*)(ws + o);                           // bf16 frag-major [2L/64][6][64][32] = 85MB
    bf16*  vt_buf = (bf16*)(ws + o + 84934656); o += 169869312;  // vt in 2nd half (disjoint)
    bf16*  h_t  = (bf16*)(ws + o); o += 169869312;           // bf16 [2][384][L] (doubles as q|k before fc1)
    bf16*  region1 = (bf16*)(ws + o); o += 169869312;        // xw -> y ; aw ; then g_t
    bf16*  xw  = region1;
    bf16*  yb  = region1;                                    // y overlays xw (dead after qkv)
    bf16*  aw  = region1 + 42467328;
    bf16*  g_t = region1;                                    // overlays y|aw after fc1
    bf16*  qkvwt  = (bf16*)(ws + o); o += 221184;
    bf16*  projwt = (bf16*)(ws + o); o += 73728;
    bf16*  fc1wt  = (bf16*)(ws + o); o += 147456;
    bf16*  fc2wt  = (bf16*)(ws + o); o += 147456;
    float* bias6  = (float*)(ws + o); o += 98304;

    bf16* q_buf  = h_t;
    bf16* k_buf  = h_t + 42467328;

    wt_frag<<<(110592 + 255) / 256, 256, 0, stream>>>(qkvw, qkvwt, 192, 576);
    wt_frag<<<(36864 + 255) / 256, 256, 0, stream>>>(projw, projwt, 192, 192);
    wt_frag<<<(73728 + 255) / 256, 256, 0, stream>>>(fc1w, fc1wt, 192, 384);
    wt_frag<<<(73728 + 255) / 256, 256, 0, stream>>>(fc2w, fc2wt, 384, 192);
    bias6_build<<<96, 256, 0, stream>>>(rpb, bias6);

    ln1_window<<<55296, 256, 0, stream>>>(x, ln1g, ln1b, xw);
    gemm_qkv<<<1728, 256, 0, stream>>>(xw, qkvwt, qkvb, q_buf, k_buf, vt_buf);
    attn_light<<<NWIN, 384, 0, stream>>>(q_buf, k_buf, vt_buf, bias6, aw);
    gemm_proj_ln<<<NWIN, 256, 0, stream>>>(aw, projwt, projb, x, ln2g, ln2b, out1, yb);
    gemm_fc1<<<1728, 256, 0, stream>>>(yb, fc1wt, fc1b, h_t);
    dwconv_bn_gelu<<<9216, 320, 0, stream>>>(h_t, dww, dwb, bng, bnb, bnm, bnv, g_t);
    gemm_fc2<<<3456, 256, 0, stream>>>(g_t, fc2wt, fc2b, out1, out);
}

// Round 17
// 741.482 us; speedup vs baseline: 1.0621x; 1.0621x over previous
//
#include <hip/hip_runtime.h>

typedef __bf16 bf16;
typedef __bf16 bf16x8 __attribute__((ext_vector_type(8)));
typedef float f32x4 __attribute__((ext_vector_type(4)));

#define L_TOT 110592   // 48^3
#define TOKS  221184   // 2*L
#define NWIN  3456     // 2*12^3

static __device__ __forceinline__ f32x4 mfma16(bf16x8 a, bf16x8 b, f32x4 c) {
    return __builtin_amdgcn_mfma_f32_16x16x32_bf16(a, b, c, 0, 0, 0);
}
static __device__ __forceinline__ bf16x8 ld8(const bf16* p) { return *(const bf16x8*)p; }

// ---------------- setup kernels ----------------
// fragment-major: dst[(((n>>6)*(K/32) + (k>>5))*64 + (n&63))*32 + (k&31)] = src[k][n]
__global__ void wt_frag(const float* __restrict__ src, bf16* __restrict__ dst, int K, int N) {
    int i = blockIdx.x * 256 + threadIdx.x;
    if (i >= K * N) return;
    int kw = i & 31, col = (i >> 5) & 63, rest = i >> 11;
    int nks = K >> 5;
    int ks = rest % nks, chunk = rest / nks;
    int n = chunk * 64 + col, k = ks * 32 + kw;
    dst[i] = (bf16)src[k * N + n];
}

__global__ void bias6_build(const float* __restrict__ rpb, float* __restrict__ bias6) {
    int i = blockIdx.x * 256 + threadIdx.x;
    if (i >= 6 * 64 * 64) return;
    int h = i >> 12, n = (i >> 6) & 63, m = i & 63;
    int r0 = (n >> 4) - (m >> 4) + 3;
    int r1 = ((n >> 2) & 3) - ((m >> 2) & 3) + 3;
    int r2 = (n & 3) - (m & 3) + 3;
    bias6[i] = rpb[(r0 * 49 + r1 * 7 + r2) * 6 + h];
}

// ---------------- LN kernels (wave per token; fragment-major output) ----------------
__global__ void ln1_window(const float* __restrict__ x, const float* __restrict__ g,
                           const float* __restrict__ bt, bf16* __restrict__ xw) {
    int wave = threadIdx.x >> 6, lane = threadIdx.x & 63;
    int t = blockIdx.x * 4 + wave;
    const float* row = x + (long)t * 192;
    float v0 = row[lane], v1 = row[lane + 64], v2 = row[lane + 128];
    float s = v0 + v1 + v2;
    #pragma unroll
    for (int m = 1; m < 64; m <<= 1) s += __shfl_xor(s, m);
    float mu = s * (1.0f / 192.0f);
    float d0 = v0 - mu, d1 = v1 - mu, d2 = v2 - mu;
    float q = d0 * d0 + d1 * d1 + d2 * d2;
    #pragma unroll
    for (int m = 1; m < 64; m <<= 1) q += __shfl_xor(q, m);
    float r = rsqrtf(q * (1.0f / 192.0f) + 1e-5f);
    int b = t / L_TOT, l = t - b * L_TOT;
    int dz = l / 2304, rem = l - dz * 2304;
    int hy = rem / 48, wx = rem - hy * 48;
    int w = ((b * 12 + (dz >> 2)) * 12 + (hy >> 2)) * 12 + (wx >> 2);
    int n = (dz & 3) * 16 + (hy & 3) * 4 + (wx & 3);
    bf16* o = xw + (long)w * 12288 + (lane >> 5) * 2048 + n * 32 + (lane & 31);
    o[0]    = (bf16)(d0 * r * g[lane]       + bt[lane]);
    o[4096] = (bf16)(d1 * r * g[lane + 64]  + bt[lane + 64]);
    o[8192] = (bf16)(d2 * r * g[lane + 128] + bt[lane + 128]);
}

__global__ void ln2_kernel(const bf16* __restrict__ in, const float* __restrict__ g,
                           const float* __restrict__ bt, bf16* __restrict__ y) {
    int wave = threadIdx.x >> 6, lane = threadIdx.x & 63;
    long t = blockIdx.x * 4 + wave;
    const bf16* row = in + t * 192;
    float v0 = (float)row[lane], v1 = (float)row[lane + 64], v2 = (float)row[lane + 128];
    float s = v0 + v1 + v2;
    #pragma unroll
    for (int m = 1; m < 64; m <<= 1) s += __shfl_xor(s, m);
    float mu = s * (1.0f / 192.0f);
    float d0 = v0 - mu, d1 = v1 - mu, d2 = v2 - mu;
    float q = d0 * d0 + d1 * d1 + d2 * d2;
    #pragma unroll
    for (int m = 1; m < 64; m <<= 1) q += __shfl_xor(q, m);
    float r = rsqrtf(q * (1.0f / 192.0f) + 1e-5f);
    bf16* o = y + (t >> 6) * 12288 + (lane >> 5) * 2048 + (t & 63) * 32 + (lane & 31);
    o[0]    = (bf16)(d0 * r * g[lane]       + bt[lane]);
    o[4096] = (bf16)(d1 * r * g[lane + 64]  + bt[lane + 64]);
    o[8192] = (bf16)(d2 * r * g[lane + 128] + bt[lane + 128]);
}

// ---------------- QKV GEMM: fragment-major A/B, coalesced fragment loads ----------------
__global__ __launch_bounds__(256) void gemm_qkv(
    const bf16* __restrict__ xw, const bf16* __restrict__ wt,
    const float* __restrict__ bqkv,
    bf16* __restrict__ qb, bf16* __restrict__ kb_, bf16* __restrict__ vtb) {
    int m0 = blockIdx.x * 128;
    int w0 = m0 >> 6;
    int wid = threadIdx.x >> 6, lane = threadIdx.x & 63;
    int wr = wid >> 1, wc = wid & 1;
    int lo = lane & 15, hi = lane >> 4;
    f32x4 zf = {0.f, 0.f, 0.f, 0.f};

    const bf16* Ab = xw + (long)(w0 + wr) * 12288 + (lo * 32 + hi * 8);
    bf16x8 a[4][6];
    #pragma unroll
    for (int ti = 0; ti < 4; ++ti)
        #pragma unroll
        for (int ks = 0; ks < 6; ++ks)
            a[ti][ks] = ld8(Ab + ks * 2048 + ti * 512);

    #pragma unroll
    for (int nc = 0; nc < 9; ++nc) {
        int sect = nc / 3;              // 0=q 1=k 2=v
        int cb0 = (nc - sect * 3) * 64;
        f32x4 acc[4][2];
        #pragma unroll
        for (int i = 0; i < 4; ++i) { acc[i][0] = zf; acc[i][1] = zf; }
        const bf16* Bb = wt + (long)nc * 12288 + (wc * 32 + lo) * 32 + hi * 8;
        #pragma unroll
        for (int ks = 0; ks < 6; ++ks) {
            bf16x8 b0 = ld8(Bb + ks * 2048);
            bf16x8 b1 = ld8(Bb + ks * 2048 + 512);
            #pragma unroll
            for (int ti = 0; ti < 4; ++ti) {
                acc[ti][0] = mfma16(a[ti][ks], b0, acc[ti][0]);
                acc[ti][1] = mfma16(a[ti][ks], b1, acc[ti][1]);
            }
        }
        #pragma unroll
        for (int ti = 0; ti < 4; ++ti)
            #pragma unroll
            for (int j = 0; j < 4; ++j) {
                int trow = m0 + wr * 64 + ti * 16 + hi * 4 + j;
                int w = trow >> 6, n = trow & 63;
                #pragma unroll
                for (int tj = 0; tj < 2; ++tj) {
                    int cw = cb0 + wc * 32 + tj * 16 + lo;   // 0..191 within section
                    int h = cw >> 5, d = cw & 31;
                    float val = acc[ti][tj][j] + bqkv[sect * 192 + cw];
                    long wh = (long)(w * 6 + h);
                    if (sect == 0)       qb[(wh * 64 + n) * 32 + d] = (bf16)(val * 0.17677669529663687f);
                    else if (sect == 1)  kb_[(wh * 64 + n) * 32 + d] = (bf16)val;
                    else                 vtb[(wh * 32 + d) * 64 + n] = (bf16)val;
                }
            }
    }
}

// ---------------- light attention: block=window, wave=head, no barriers ----------------
__global__ __launch_bounds__(384) void attn_light(
    const bf16* __restrict__ qb, const bf16* __restrict__ kb_,
    const bf16* __restrict__ vtb, const float* __restrict__ bias6,
    bf16* __restrict__ aw) {
    __shared__ char p_smem[6 * 8192];   // per head: [64][64] bf16 XOR-swizzled
    int w = blockIdx.x;
    int h = threadIdx.x >> 6;
    int lane = threadIdx.x & 63;
    int lo = lane & 15, hi = lane >> 4;
    char* ph = p_smem + h * 8192;
    long wh = (long)(w * 6 + h);
    f32x4 zf = {0.f, 0.f, 0.f, 0.f};

    bf16x8 qa[4], kb[4];
    #pragma unroll
    for (int ti = 0; ti < 4; ++ti) qa[ti] = ld8(qb  + (wh * 64 + ti * 16 + lo) * 32 + hi * 8);
    #pragma unroll
    for (int tj = 0; tj < 4; ++tj) kb[tj] = ld8(kb_ + (wh * 64 + tj * 16 + lo) * 32 + hi * 8);
    f32x4 s[4][4];
    #pragma unroll
    for (int ti = 0; ti < 4; ++ti)
        #pragma unroll
        for (int tj = 0; tj < 4; ++tj)
            s[ti][tj] = mfma16(qa[ti], kb[tj], zf);

    const float* bh = bias6 + h * 4096;
    #pragma unroll
    for (int ti = 0; ti < 4; ++ti)
        #pragma unroll
        for (int j = 0; j < 4; ++j) {
            int rr = ti * 16 + hi * 4 + j;
            float ev[4];
            #pragma unroll
            for (int tj = 0; tj < 4; ++tj) s[ti][tj][j] += bh[rr * 64 + tj * 16 + lo];
            float mx = fmaxf(fmaxf(s[ti][0][j], s[ti][1][j]), fmaxf(s[ti][2][j], s[ti][3][j]));
            #pragma unroll
            for (int m = 1; m < 16; m <<= 1) mx = fmaxf(mx, __shfl_xor(mx, m));
            float sum = 0.f;
            #pragma unroll
            for (int tj = 0; tj < 4; ++tj) { ev[tj] = __expf(s[ti][tj][j] - mx); sum += ev[tj]; }
            #pragma unroll
            for (int m = 1; m < 16; m <<= 1) sum += __shfl_xor(sum, m);
            float inv = 1.0f / sum;
            #pragma unroll
            for (int tj = 0; tj < 4; ++tj) {
                int byte = ((rr * 64 + tj * 16 + lo) * 2) ^ ((rr & 7) << 4);
                *(bf16*)(ph + byte) = (bf16)(ev[tj] * inv);
            }
        }

    f32x4 o[4][2];
    #pragma unroll
    for (int i = 0; i < 4; ++i) { o[i][0] = zf; o[i][1] = zf; }
    #pragma unroll
    for (int ks2 = 0; ks2 < 2; ++ks2) {
        bf16x8 pa[4], vb[2];
        #pragma unroll
        for (int ti = 0; ti < 4; ++ti) {
            int row = ti * 16 + lo;
            pa[ti] = *(const bf16x8*)(ph + ((row * 128 + ks2 * 64 + hi * 16) ^ ((row & 7) << 4)));
        }
        #pragma unroll
        for (int td = 0; td < 2; ++td)
            vb[td] = ld8(vtb + (wh * 32 + td * 16 + lo) * 64 + ks2 * 32 + hi * 8);
        #pragma unroll
        for (int ti = 0; ti < 4; ++ti)
            #pragma unroll
            for (int td = 0; td < 2; ++td)
                o[ti][td] = mfma16(pa[ti], vb[td], o[ti][td]);
    }
    // fragment-major aw: [w][h][n][32]
    bf16* orow = aw + wh * 2048;
    #pragma unroll
    for (int ti = 0; ti < 4; ++ti)
        #pragma unroll
        for (int td = 0; td < 2; ++td)
            #pragma unroll
            for (int j = 0; j < 4; ++j)
                orow[(ti * 16 + hi * 4 + j) * 32 + td * 16 + lo] = (bf16)o[ti][td][j];
}

// ---------------- proj GEMM: fragment-major A/B, unwindow + residual (bf16 out1 row-major) ----------------
__global__ __launch_bounds__(256) void gemm_proj(
    const bf16* __restrict__ aw, const bf16* __restrict__ wt,
    const float* __restrict__ bias, const float* __restrict__ x,
    bf16* __restrict__ out1) {
    int m0 = blockIdx.x * 128;
    int w0 = m0 >> 6;
    int wid = threadIdx.x >> 6, lane = threadIdx.x & 63;
    int wr = wid >> 1, wc = wid & 1;
    int lo = lane & 15, hi = lane >> 4;
    f32x4 zf = {0.f, 0.f, 0.f, 0.f};

    const bf16* Ab = aw + (long)(w0 + wr) * 12288 + (lo * 32 + hi * 8);
    bf16x8 a[4][6];
    #pragma unroll
    for (int ti = 0; ti < 4; ++ti)
        #pragma unroll
        for (int ks = 0; ks < 6; ++ks)
            a[ti][ks] = ld8(Ab + ks * 2048 + ti * 512);

    #pragma unroll
    for (int nc = 0; nc < 3; ++nc) {
        f32x4 acc[4][2];
        #pragma unroll
        for (int i = 0; i < 4; ++i) { acc[i][0] = zf; acc[i][1] = zf; }
        const bf16* Bb = wt + (long)nc * 12288 + (wc * 32 + lo) * 32 + hi * 8;
        #pragma unroll
        for (int ks = 0; ks < 6; ++ks) {
            bf16x8 b0 = ld8(Bb + ks * 2048);
            bf16x8 b1 = ld8(Bb + ks * 2048 + 512);
            #pragma unroll
            for (int ti = 0; ti < 4; ++ti) {
                acc[ti][0] = mfma16(a[ti][ks], b0, acc[ti][0]);
                acc[ti][1] = mfma16(a[ti][ks], b1, acc[ti][1]);
            }
        }
        #pragma unroll
        for (int ti = 0; ti < 4; ++ti)
            #pragma unroll
            for (int j = 0; j < 4; ++j) {
                int trow = m0 + wr * 64 + ti * 16 + hi * 4 + j;
                int wv = trow >> 6, n = trow & 63;
                int bb = wv / 1728; int rem = wv - bb * 1728;
                int dq = rem / 144; int rem2 = rem - dq * 144;
                int hq = rem2 / 12; int wq = rem2 - hq * 12;
                int l = (dq * 4 + (n >> 4)) * 2304 + (hq * 4 + ((n >> 2) & 3)) * 48 + (wq * 4 + (n & 3));
                long base = ((long)bb * L_TOT + l) * 192;
                #pragma unroll
                for (int tj = 0; tj < 2; ++tj) {
                    int col = nc * 64 + wc * 32 + tj * 16 + lo;
                    out1[base + col] = (bf16)(x[base + col] + acc[ti][tj][j] + bias[col]);
                }
            }
    }
}

// ---------------- fc1 GEMM: fragment-major A/B, transpose epilogue ----------------
__global__ __launch_bounds__(256) void gemm_fc1(
    const bf16* __restrict__ y, const bf16* __restrict__ wt,
    const float* __restrict__ bias, bf16* __restrict__ h_t) {
    __shared__ bf16 tl[64][136];
    int m0 = blockIdx.x * 128;
    int c0 = m0 >> 6;
    int wid = threadIdx.x >> 6, lane = threadIdx.x & 63;
    int wr = wid >> 1, wc = wid & 1;
    int lo = lane & 15, hi = lane >> 4;
    f32x4 zf = {0.f, 0.f, 0.f, 0.f};
    int bb = m0 / L_TOT; int l0 = m0 - bb * L_TOT;
    int col = threadIdx.x >> 2, seg = threadIdx.x & 3;

    const bf16* Ab = y + (long)(c0 + wr) * 12288 + (lo * 32 + hi * 8);
    bf16x8 a[4][6];
    #pragma unroll
    for (int ti = 0; ti < 4; ++ti)
        #pragma unroll
        for (int ks = 0; ks < 6; ++ks)
            a[ti][ks] = ld8(Ab + ks * 2048 + ti * 512);

    #pragma unroll
    for (int nc = 0; nc < 6; ++nc) {
        f32x4 acc[4][2];
        #pragma unroll
        for (int i = 0; i < 4; ++i) { acc[i][0] = zf; acc[i][1] = zf; }
        const bf16* Bb = wt + (long)nc * 12288 + (wc * 32 + lo) * 32 + hi * 8;
        #pragma unroll
        for (int ks = 0; ks < 6; ++ks) {
            bf16x8 b0 = ld8(Bb + ks * 2048);
            bf16x8 b1 = ld8(Bb + ks * 2048 + 512);
            #pragma unroll
            for (int ti = 0; ti < 4; ++ti) {
                acc[ti][0] = mfma16(a[ti][ks], b0, acc[ti][0]);
                acc[ti][1] = mfma16(a[ti][ks], b1, acc[ti][1]);
            }
        }
        if (nc) __syncthreads();
        #pragma unroll
        for (int ti = 0; ti < 4; ++ti)
            #pragma unroll
            for (int tj = 0; tj < 2; ++tj)
                #pragma unroll
                for (int j = 0; j < 4; ++j) {
                    int rl = wr * 64 + ti * 16 + hi * 4 + j;
                    int cl = wc * 32 + tj * 16 + lo;
                    tl[cl][rl] = (bf16)(acc[ti][tj][j] + bias[nc * 64 + cl]);
                }
        __syncthreads();
        bf16* dst = h_t + ((long)bb * 384 + nc * 64 + col) * L_TOT + l0 + seg * 32;
        #pragma unroll
        for (int i8 = 0; i8 < 4; ++i8)
            *(bf16x8*)(dst + i8 * 8) = *(const bf16x8*)(&tl[col][seg * 32 + i8 * 8]);
    }
}

// ---------------- depthwise conv 3^3 + BN + GELU (slab=4, stride-56 LDS, division-free staging) ----------------
__global__ __launch_bounds__(320) void dwconv_bn_gelu(
    const bf16* __restrict__ h_t, const float* __restrict__ wconv,
    const float* __restrict__ cb, const float* __restrict__ bng,
    const float* __restrict__ bnb, const float* __restrict__ bnm,
    const float* __restrict__ bnv, bf16* __restrict__ g_t) {
    // 1 guard row + 6*48 data rows, stride 56; cols 48..55 of every row are zero. 32368B -> 5 blocks/CU.
    __shared__ __align__(16) bf16 tile[289 * 56];
    int blk = blockIdx.x;
    int bb = blk / 4608; int rem = blk - bb * 4608;
    int ch = rem / 12; int zb = rem - ch * 12; int z0 = zb * 4;
    const bf16* src = h_t + ((long)bb * 384 + ch) * L_TOT;

    int y = threadIdx.x / 6, cx = threadIdx.x - y * 6, x0 = cx * 8;
    bool active = threadIdx.x < 288;

    // zero guard cells: guard row (7 uint4) + right columns (48..55) of 288 data rows
    uint4 zv = make_uint4(0u, 0u, 0u, 0u);
    for (int i = threadIdx.x; i < 295; i += 320) {
        int e = (i < 7) ? i * 8 : ((i - 7 + 1) * 56 + 48);
        *(uint4*)(tile + e) = zv;
    }
    // stage 6 planes x 48 rows x 48 cols, division-free (thread's own (y,cx)), 16B-aligned writes
    if (active) {
        #pragma unroll
        for (int zi = 0; zi < 6; ++zi) {
            int gz = z0 - 1 + zi;
            uint4 val = zv;
            if (gz >= 0 && gz < 48) val = *(const uint4*)(src + (long)gz * 2304 + y * 48 + x0);
            *(uint4*)(tile + (1 + zi * 48 + y) * 56 + x0) = val;
        }
    }
    float wgt[27];
    #pragma unroll
    for (int i = 0; i < 27; ++i) wgt[i] = wconv[ch * 27 + i];
    float scale = bng[ch] * rsqrtf(bnv[ch] + 1e-5f);
    float shift = bnb[ch] - bnm[ch] * scale;
    float cbias = cb[ch];
    __syncthreads();

    if (active) {
        __builtin_assume(y < 48);
        bool up_ok = (y > 0), dn_ok = (y < 47);
        bf16* dstc = g_t + ((long)bb * 384 + ch) * L_TOT + (long)z0 * 2304 + y * 48 + x0;
        float acc[4][8];
        #pragma unroll
        for (int p = 0; p < 4; ++p)
            #pragma unroll
            for (int k = 0; k < 8; ++k) acc[p][k] = 0.f;

        #pragma unroll
        for (int zi = 0; zi < 6; ++zi) {
            const bf16* plane = tile + (1 + zi * 48) * 56;
            #pragma unroll
            for (int dy = 0; dy < 3; ++dy) {
                bool ok = (dy == 1) || (dy == 0 ? up_ok : dn_ok);
                if (ok) {
                    const bf16* rp = plane + (y + dy - 1) * 56 + x0;
                    bf16x8 mv = ld8(rp);            // single ds_read_b128 (16B aligned)
                    float s[10];
                    s[0] = (float)rp[-1];           // cx==0 -> prev row col 55 == 0
                    #pragma unroll
                    for (int i = 0; i < 8; ++i) s[i + 1] = (float)mv[i];
                    s[9] = (float)rp[8];            // cx==5 -> col 48 == 0
                    #pragma unroll
                    for (int dz = 0; dz < 3; ++dz) {
                        int p = zi - dz;
                        if (p >= 0 && p <= 3) {     // compile-time after unroll
                            float w0 = wgt[dz * 9 + dy * 3 + 0];
                            float w1 = wgt[dz * 9 + dy * 3 + 1];
                            float w2 = wgt[dz * 9 + dy * 3 + 2];
                            #pragma unroll
                            for (int k = 0; k < 8; ++k)
                                acc[p][k] = fmaf(w0, s[k], fmaf(w1, s[k + 1], fmaf(w2, s[k + 2], acc[p][k])));
                        }
                    }
                }
            }
            if (zi >= 2) {
                int p = zi - 2;
                bf16x8 ov;
                #pragma unroll
                for (int k = 0; k < 8; ++k) {
                    float v = acc[p][k] + cbias;
                    v = fmaf(v, scale, shift);
                    // GELU tanh form via exp2 (log2e folded): v - v/(2^(u2) + 1)
                    float v2 = v * v;
                    float u2 = v * fmaf(v2, 0.10294357f, 2.3022080918f);
                    float e  = exp2f(u2);
                    float q  = __builtin_amdgcn_rcpf(e + 1.0f);
                    ov[k] = (bf16)(v - v * q);
                }
                *(bf16x8*)(dstc + p * 2304) = ov;
            }
        }
    }
}

// ---------------- fc2 GEMM: M=64, 2-deep prefetch, early residual preload ----------------
__global__ __launch_bounds__(256) void gemm_fc2(
    const bf16* __restrict__ g_t, const bf16* __restrict__ wt,
    const float* __restrict__ bias, const bf16* __restrict__ out1,
    float* __restrict__ out) {
    __shared__ bf16 As[2][4096];        // [64 tok][64 ch], elem = tok*64 + (ch ^ (S(tok)<<3))
    int m0 = blockIdx.x * 64;
    int wc = threadIdx.x >> 6, lane = threadIdx.x & 63;
    int lo = lane & 15, hi = lane >> 4;
    int bb = m0 / L_TOT, l0 = m0 - bb * L_TOT;
    f32x4 zf = {0.f, 0.f, 0.f, 0.f};
    f32x4 acc[3][4];                    // [tj][ti]
    #pragma unroll
    for (int tj = 0; tj < 3; ++tj)
        #pragma unroll
        for (int ti = 0; ti < 4; ++ti) acc[tj][ti] = zf;

    int sch = threadIdx.x >> 3;          // channel within pass (0..31)
    int seg = threadIdx.x & 7;           // 8-token segment
    const bf16* srcb = g_t + ((long)bb * 384 + sch) * L_TOT + l0 + seg * 8;

    bf16x8 r[2][2];
    // tile 0 -> As[0]
    #pragma unroll
    for (int p = 0; p < 2; ++p) r[0][p] = ld8(srcb + (long)(p * 32) * L_TOT);
    #pragma unroll
    for (int p = 0; p < 2; ++p)
        #pragma unroll
        for (int i = 0; i < 8; ++i)
            As[0][(seg * 8 + i) * 64 + ((p * 32 + sch) ^ (((seg ^ i) & 7) << 3))] = r[0][p][i];
    // 2-deep prefetch: tiles 1 and 2
    #pragma unroll
    for (int p = 0; p < 2; ++p) r[0][p] = ld8(srcb + (long)(64 + p * 32) * L_TOT);
    #pragma unroll
    for (int p = 0; p < 2; ++p) r[1][p] = ld8(srcb + (long)(128 + p * 32) * L_TOT);

    // early residual preload (overlaps the whole GEMM)
    float res[3][4][4];
    #pragma unroll
    for (int tj = 0; tj < 3; ++tj)
        #pragma unroll
        for (int ti = 0; ti < 4; ++ti)
            #pragma unroll
            for (int j = 0; j < 4; ++j) {
                long trow = m0 + ti * 16 + hi * 4 + j;
                res[tj][ti][j] = (float)out1[trow * 192 + wc * 48 + tj * 16 + lo];
            }
    __syncthreads();

    #pragma unroll
    for (int t = 0; t < 6; ++t) {
        const bf16* Ac = As[t & 1];
        #pragma unroll
        for (int ksin = 0; ksin < 2; ++ksin) {
            bf16x8 a[4];
            #pragma unroll
            for (int ti = 0; ti < 4; ++ti) {
                int rr = ti * 16 + lo;
                int S = ((rr >> 3) ^ rr) & 7;
                a[ti] = *(const bf16x8*)&Ac[rr * 64 + ((ksin * 32 + hi * 8) ^ (S << 3))];
            }
            #pragma unroll
            for (int tj = 0; tj < 3; ++tj) {
                int cstart = wc * 48 + tj * 16;
                bf16x8 b0 = ld8(wt + ((long)((cstart >> 6) * 12 + t * 2 + ksin) * 64 + (cstart & 63) + lo) * 32 + hi * 8);
                #pragma unroll
                for (int ti = 0; ti < 4; ++ti)
                    acc[tj][ti] = mfma16(a[ti], b0, acc[tj][ti]);
            }
        }
        if (t < 5) {
            bf16* An = As[(t + 1) & 1];
            #pragma unroll
            for (int p = 0; p < 2; ++p)
                #pragma unroll
                for (int i = 0; i < 8; ++i)
                    An[(seg * 8 + i) * 64 + ((p * 32 + sch) ^ (((seg ^ i) & 7) << 3))] = r[t & 1][p][i];
        }
        if (t < 3) {
            #pragma unroll
            for (int p = 0; p < 2; ++p)
                r[t & 1][p] = ld8(srcb + (long)((t + 3) * 64 + p * 32) * L_TOT);
        }
        __syncthreads();
    }
    #pragma unroll
    for (int tj = 0; tj < 3; ++tj)
        #pragma unroll
        for (int ti = 0; ti < 4; ++ti)
            #pragma unroll
            for (int j = 0; j < 4; ++j) {
                long trow = m0 + ti * 16 + hi * 4 + j;
                int col = wc * 48 + tj * 16 + lo;
                out[trow * 192 + col] = res[tj][ti][j] + acc[tj][ti][j] + bias[col];
            }
}

// ---------------- host ----------------
extern "C" void kernel_launch(void* const* d_in, const int* in_sizes, int n_in,
                              void* d_out, int out_size, void* d_ws, size_t ws_size,
                              hipStream_t stream) {
    (void)in_sizes; (void)n_in; (void)out_size; (void)ws_size;
    const float* x     = (const float*)d_in[0];
    const float* ln1g  = (const float*)d_in[4];
    const float* ln1b  = (const float*)d_in[5];
    const float* ln2g  = (const float*)d_in[6];
    const float* ln2b  = (const float*)d_in[7];
    const float* qkvw  = (const float*)d_in[8];
    const float* qkvb  = (const float*)d_in[9];
    const float* rpb   = (const float*)d_in[10];
    const float* projw = (const float*)d_in[11];
    const float* projb = (const float*)d_in[12];
    const float* fc1w  = (const float*)d_in[13];
    const float* fc1b  = (const float*)d_in[14];
    const float* dww   = (const float*)d_in[15];
    const float* dwb   = (const float*)d_in[16];
    const float* bng   = (const float*)d_in[17];
    const float* bnb   = (const float*)d_in[18];
    const float* bnm   = (const float*)d_in[19];
    const float* bnv   = (const float*)d_in[20];
    const float* fc2w  = (const float*)d_in[21];
    const float* fc2b  = (const float*)d_in[22];
    float* out = (float*)d_out;

    char* ws = (char*)d_ws;
    size_t o = 0;
    bf16*  out1 = (bf16*)(ws + o);                           // bf16 [2][L][192] = 85MB
    bf16*  vt_buf = (bf16*)(ws + o + 84934656); o += 169869312;  // vt in 2nd half (disjoint)
    bf16*  h_t  = (bf16*)(ws + o); o += 169869312;           // bf16 [2][384][L] (doubles as q|k before fc1)
    bf16*  region1 = (bf16*)(ws + o); o += 169869312;        // xw|aw -> y -> g_t
    bf16*  xw  = region1;
    bf16*  aw  = region1 + 42467328;
    bf16*  yb  = region1;
    bf16*  g_t = region1;
    bf16*  qkvwt  = (bf16*)(ws + o); o += 221184;
    bf16*  projwt = (bf16*)(ws + o); o += 73728;
    bf16*  fc1wt  = (bf16*)(ws + o); o += 147456;
    bf16*  fc2wt  = (bf16*)(ws + o); o += 147456;
    float* bias6  = (float*)(ws + o); o += 98304;

    bf16* q_buf  = h_t;
    bf16* k_buf  = h_t + 42467328;

    wt_frag<<<(110592 + 255) / 256, 256, 0, stream>>>(qkvw, qkvwt, 192, 576);
    wt_frag<<<(36864 + 255) / 256, 256, 0, stream>>>(projw, projwt, 192, 192);
    wt_frag<<<(73728 + 255) / 256, 256, 0, stream>>>(fc1w, fc1wt, 192, 384);
    wt_frag<<<(73728 + 255) / 256, 256, 0, stream>>>(fc2w, fc2wt, 384, 192);
    bias6_build<<<96, 256, 0, stream>>>(rpb, bias6);

    ln1_window<<<55296, 256, 0, stream>>>(x, ln1g, ln1b, xw);
    gemm_qkv<<<1728, 256, 0, stream>>>(xw, qkvwt, qkvb, q_buf, k_buf, vt_buf);
    attn_light<<<NWIN, 384, 0, stream>>>(q_buf, k_buf, vt_buf, bias6, aw);
    gemm_proj<<<1728, 256, 0, stream>>>(aw, projwt, projb, x, out1);
    ln2_kernel<<<55296, 256, 0, stream>>>(out1, ln2g, ln2b, yb);
    gemm_fc1<<<1728, 256, 0, stream>>>(yb, fc1wt, fc1b, h_t);
    dwconv_bn_gelu<<<9216, 320, 0, stream>>>(h_t, dww, dwb, bng, bnb, bnm, bnv, g_t);
    gemm_fc2<<<3456, 256, 0, stream>>>(g_t, fc2wt, fc2b, out1, out);
}

// Round 18
// 731.919 us; speedup vs baseline: 1.0759x; 1.0131x over previous
//
#include <hip/hip_runtime.h>

typedef __bf16 bf16;
typedef __bf16 bf16x8 __attribute__((ext_vector_type(8)));
typedef float f32x4 __attribute__((ext_vector_type(4)));

#define L_TOT 110592   // 48^3
#define TOKS  221184   // 2*L
#define NWIN  3456     // 2*12^3

static __device__ __forceinline__ f32x4 mfma16(bf16x8 a, bf16x8 b, f32x4 c) {
    return __builtin_amdgcn_mfma_f32_16x16x32_bf16(a, b, c, 0, 0, 0);
}
static __device__ __forceinline__ bf16x8 ld8(const bf16* p) { return *(const bf16x8*)p; }

// ---------------- merged setup: 4 weight frag-transposes + bias6 in one launch ----------------
// fragment-major: dst[(((n>>6)*(K/32) + (k>>5))*64 + (n&63))*32 + (k&31)] = src[k][n]
static __device__ __forceinline__ void frag_one(const float* __restrict__ src, bf16* __restrict__ dst,
                                                int i, int K, int N) {
    int kw = i & 31, col = (i >> 5) & 63, rest = i >> 11;
    int nks = K >> 5;
    int ks = rest % nks, chunk = rest / nks;
    int n = chunk * 64 + col, k = ks * 32 + kw;
    dst[i] = (bf16)src[k * N + n];
}

__global__ void setup_all(const float* __restrict__ qkvw, const float* __restrict__ projw,
                          const float* __restrict__ fc1w, const float* __restrict__ fc2w,
                          const float* __restrict__ rpb,
                          bf16* __restrict__ qkvwt, bf16* __restrict__ projwt,
                          bf16* __restrict__ fc1wt, bf16* __restrict__ fc2wt,
                          float* __restrict__ bias6) {
    int i = blockIdx.x * 256 + threadIdx.x;
    if (i < 110592) {
        frag_one(qkvw, qkvwt, i, 192, 576);
    } else if (i < 147456) {
        frag_one(projw, projwt, i - 110592, 192, 192);
    } else if (i < 221184) {
        frag_one(fc1w, fc1wt, i - 147456, 192, 384);
    } else if (i < 294912) {
        frag_one(fc2w, fc2wt, i - 221184, 384, 192);
    } else if (i < 319488) {
        int j = i - 294912;
        int h = j >> 12, n = (j >> 6) & 63, m = j & 63;
        int r0 = (n >> 4) - (m >> 4) + 3;
        int r1 = ((n >> 2) & 3) - ((m >> 2) & 3) + 3;
        int r2 = (n & 3) - (m & 3) + 3;
        bias6[j] = rpb[(r0 * 49 + r1 * 7 + r2) * 6 + h];
    }
}

// ---------------- LN kernels (wave per token; fragment-major output) ----------------
__global__ void ln1_window(const float* __restrict__ x, const float* __restrict__ g,
                           const float* __restrict__ bt, bf16* __restrict__ xw) {
    int wave = threadIdx.x >> 6, lane = threadIdx.x & 63;
    int t = blockIdx.x * 4 + wave;
    const float* row = x + (long)t * 192;
    float v0 = row[lane], v1 = row[lane + 64], v2 = row[lane + 128];
    float s = v0 + v1 + v2;
    #pragma unroll
    for (int m = 1; m < 64; m <<= 1) s += __shfl_xor(s, m);
    float mu = s * (1.0f / 192.0f);
    float d0 = v0 - mu, d1 = v1 - mu, d2 = v2 - mu;
    float q = d0 * d0 + d1 * d1 + d2 * d2;
    #pragma unroll
    for (int m = 1; m < 64; m <<= 1) q += __shfl_xor(q, m);
    float r = rsqrtf(q * (1.0f / 192.0f) + 1e-5f);
    int b = t / L_TOT, l = t - b * L_TOT;
    int dz = l / 2304, rem = l - dz * 2304;
    int hy = rem / 48, wx = rem - hy * 48;
    int w = ((b * 12 + (dz >> 2)) * 12 + (hy >> 2)) * 12 + (wx >> 2);
    int n = (dz & 3) * 16 + (hy & 3) * 4 + (wx & 3);
    bf16* o = xw + (long)w * 12288 + (lane >> 5) * 2048 + n * 32 + (lane & 31);
    o[0]    = (bf16)(d0 * r * g[lane]       + bt[lane]);
    o[4096] = (bf16)(d1 * r * g[lane + 64]  + bt[lane + 64]);
    o[8192] = (bf16)(d2 * r * g[lane + 128] + bt[lane + 128]);
}

__global__ void ln2_kernel(const bf16* __restrict__ in, const float* __restrict__ g,
                           const float* __restrict__ bt, bf16* __restrict__ y) {
    int wave = threadIdx.x >> 6, lane = threadIdx.x & 63;
    long t = blockIdx.x * 4 + wave;
    const bf16* row = in + t * 192;
    float v0 = (float)row[lane], v1 = (float)row[lane + 64], v2 = (float)row[lane + 128];
    float s = v0 + v1 + v2;
    #pragma unroll
    for (int m = 1; m < 64; m <<= 1) s += __shfl_xor(s, m);
    float mu = s * (1.0f / 192.0f);
    float d0 = v0 - mu, d1 = v1 - mu, d2 = v2 - mu;
    float q = d0 * d0 + d1 * d1 + d2 * d2;
    #pragma unroll
    for (int m = 1; m < 64; m <<= 1) q += __shfl_xor(q, m);
    float r = rsqrtf(q * (1.0f / 192.0f) + 1e-5f);
    bf16* o = y + (t >> 6) * 12288 + (lane >> 5) * 2048 + (t & 63) * 32 + (lane & 31);
    o[0]    = (bf16)(d0 * r * g[lane]       + bt[lane]);
    o[4096] = (bf16)(d1 * r * g[lane + 64]  + bt[lane + 64]);
    o[8192] = (bf16)(d2 * r * g[lane + 128] + bt[lane + 128]);
}

// ---------------- QKV GEMM: fragment-major A/B, coalesced fragment loads ----------------
__global__ __launch_bounds__(256) void gemm_qkv(
    const bf16* __restrict__ xw, const bf16* __restrict__ wt,
    const float* __restrict__ bqkv,
    bf16* __restrict__ qb, bf16* __restrict__ kb_, bf16* __restrict__ vtb) {
    int m0 = blockIdx.x * 128;
    int w0 = m0 >> 6;
    int wid = threadIdx.x >> 6, lane = threadIdx.x & 63;
    int wr = wid >> 1, wc = wid & 1;
    int lo = lane & 15, hi = lane >> 4;
    f32x4 zf = {0.f, 0.f, 0.f, 0.f};

    const bf16* Ab = xw + (long)(w0 + wr) * 12288 + (lo * 32 + hi * 8);
    bf16x8 a[4][6];
    #pragma unroll
    for (int ti = 0; ti < 4; ++ti)
        #pragma unroll
        for (int ks = 0; ks < 6; ++ks)
            a[ti][ks] = ld8(Ab + ks * 2048 + ti * 512);

    #pragma unroll
    for (int nc = 0; nc < 9; ++nc) {
        int sect = nc / 3;              // 0=q 1=k 2=v
        int cb0 = (nc - sect * 3) * 64;
        f32x4 acc[4][2];
        #pragma unroll
        for (int i = 0; i < 4; ++i) { acc[i][0] = zf; acc[i][1] = zf; }
        const bf16* Bb = wt + (long)nc * 12288 + (wc * 32 + lo) * 32 + hi * 8;
        #pragma unroll
        for (int ks = 0; ks < 6; ++ks) {
            bf16x8 b0 = ld8(Bb + ks * 2048);
            bf16x8 b1 = ld8(Bb + ks * 2048 + 512);
            #pragma unroll
            for (int ti = 0; ti < 4; ++ti) {
                acc[ti][0] = mfma16(a[ti][ks], b0, acc[ti][0]);
                acc[ti][1] = mfma16(a[ti][ks], b1, acc[ti][1]);
            }
        }
        #pragma unroll
        for (int ti = 0; ti < 4; ++ti)
            #pragma unroll
            for (int j = 0; j < 4; ++j) {
                int trow = m0 + wr * 64 + ti * 16 + hi * 4 + j;
                int w = trow >> 6, n = trow & 63;
                #pragma unroll
                for (int tj = 0; tj < 2; ++tj) {
                    int cw = cb0 + wc * 32 + tj * 16 + lo;   // 0..191 within section
                    int h = cw >> 5, d = cw & 31;
                    float val = acc[ti][tj][j] + bqkv[sect * 192 + cw];
                    long wh = (long)(w * 6 + h);
                    if (sect == 0)       qb[(wh * 64 + n) * 32 + d] = (bf16)(val * 0.17677669529663687f);
                    else if (sect == 1)  kb_[(wh * 64 + n) * 32 + d] = (bf16)val;
                    else                 vtb[(wh * 32 + d) * 64 + n] = (bf16)val;
                }
            }
    }
}

// ---------------- light attention: block=window, wave=head, no barriers ----------------
__global__ __launch_bounds__(384) void attn_light(
    const bf16* __restrict__ qb, const bf16* __restrict__ kb_,
    const bf16* __restrict__ vtb, const float* __restrict__ bias6,
    bf16* __restrict__ aw) {
    __shared__ char p_smem[6 * 8192];   // per head: [64][64] bf16 XOR-swizzled
    int w = blockIdx.x;
    int h = threadIdx.x >> 6;
    int lane = threadIdx.x & 63;
    int lo = lane & 15, hi = lane >> 4;
    char* ph = p_smem + h * 8192;
    long wh = (long)(w * 6 + h);
    f32x4 zf = {0.f, 0.f, 0.f, 0.f};

    bf16x8 qa[4], kb[4];
    #pragma unroll
    for (int ti = 0; ti < 4; ++ti) qa[ti] = ld8(qb  + (wh * 64 + ti * 16 + lo) * 32 + hi * 8);
    #pragma unroll
    for (int tj = 0; tj < 4; ++tj) kb[tj] = ld8(kb_ + (wh * 64 + tj * 16 + lo) * 32 + hi * 8);
    f32x4 s[4][4];
    #pragma unroll
    for (int ti = 0; ti < 4; ++ti)
        #pragma unroll
        for (int tj = 0; tj < 4; ++tj)
            s[ti][tj] = mfma16(qa[ti], kb[tj], zf);

    const float* bh = bias6 + h * 4096;
    #pragma unroll
    for (int ti = 0; ti < 4; ++ti)
        #pragma unroll
        for (int j = 0; j < 4; ++j) {
            int rr = ti * 16 + hi * 4 + j;
            float ev[4];
            #pragma unroll
            for (int tj = 0; tj < 4; ++tj) s[ti][tj][j] += bh[rr * 64 + tj * 16 + lo];
            float mx = fmaxf(fmaxf(s[ti][0][j], s[ti][1][j]), fmaxf(s[ti][2][j], s[ti][3][j]));
            #pragma unroll
            for (int m = 1; m < 16; m <<= 1) mx = fmaxf(mx, __shfl_xor(mx, m));
            float sum = 0.f;
            #pragma unroll
            for (int tj = 0; tj < 4; ++tj) { ev[tj] = __expf(s[ti][tj][j] - mx); sum += ev[tj]; }
            #pragma unroll
            for (int m = 1; m < 16; m <<= 1) sum += __shfl_xor(sum, m);
            float inv = 1.0f / sum;
            #pragma unroll
            for (int tj = 0; tj < 4; ++tj) {
                int byte = ((rr * 64 + tj * 16 + lo) * 2) ^ ((rr & 7) << 4);
                *(bf16*)(ph + byte) = (bf16)(ev[tj] * inv);
            }
        }

    f32x4 o[4][2];
    #pragma unroll
    for (int i = 0; i < 4; ++i) { o[i][0] = zf; o[i][1] = zf; }
    #pragma unroll
    for (int ks2 = 0; ks2 < 2; ++ks2) {
        bf16x8 pa[4], vb[2];
        #pragma unroll
        for (int ti = 0; ti < 4; ++ti) {
            int row = ti * 16 + lo;
            pa[ti] = *(const bf16x8*)(ph + ((row * 128 + ks2 * 64 + hi * 16) ^ ((row & 7) << 4)));
        }
        #pragma unroll
        for (int td = 0; td < 2; ++td)
            vb[td] = ld8(vtb + (wh * 32 + td * 16 + lo) * 64 + ks2 * 32 + hi * 8);
        #pragma unroll
        for (int ti = 0; ti < 4; ++ti)
            #pragma unroll
            for (int td = 0; td < 2; ++td)
                o[ti][td] = mfma16(pa[ti], vb[td], o[ti][td]);
    }
    // fragment-major aw: [w][h][n][32]
    bf16* orow = aw + wh * 2048;
    #pragma unroll
    for (int ti = 0; ti < 4; ++ti)
        #pragma unroll
        for (int td = 0; td < 2; ++td)
            #pragma unroll
            for (int j = 0; j < 4; ++j)
                orow[(ti * 16 + hi * 4 + j) * 32 + td * 16 + lo] = (bf16)o[ti][td][j];
}

// ---------------- proj GEMM: fragment-major A/B, unwindow + residual (bf16 out1 row-major) ----------------
__global__ __launch_bounds__(256) void gemm_proj(
    const bf16* __restrict__ aw, const bf16* __restrict__ wt,
    const float* __restrict__ bias, const float* __restrict__ x,
    bf16* __restrict__ out1) {
    int m0 = blockIdx.x * 128;
    int w0 = m0 >> 6;
    int wid = threadIdx.x >> 6, lane = threadIdx.x & 63;
    int wr = wid >> 1, wc = wid & 1;
    int lo = lane & 15, hi = lane >> 4;
    f32x4 zf = {0.f, 0.f, 0.f, 0.f};

    const bf16* Ab = aw + (long)(w0 + wr) * 12288 + (lo * 32 + hi * 8);
    bf16x8 a[4][6];
    #pragma unroll
    for (int ti = 0; ti < 4; ++ti)
        #pragma unroll
        for (int ks = 0; ks < 6; ++ks)
            a[ti][ks] = ld8(Ab + ks * 2048 + ti * 512);

    #pragma unroll
    for (int nc = 0; nc < 3; ++nc) {
        f32x4 acc[4][2];
        #pragma unroll
        for (int i = 0; i < 4; ++i) { acc[i][0] = zf; acc[i][1] = zf; }
        const bf16* Bb = wt + (long)nc * 12288 + (wc * 32 + lo) * 32 + hi * 8;
        #pragma unroll
        for (int ks = 0; ks < 6; ++ks) {
            bf16x8 b0 = ld8(Bb + ks * 2048);
            bf16x8 b1 = ld8(Bb + ks * 2048 + 512);
            #pragma unroll
            for (int ti = 0; ti < 4; ++ti) {
                acc[ti][0] = mfma16(a[ti][ks], b0, acc[ti][0]);
                acc[ti][1] = mfma16(a[ti][ks], b1, acc[ti][1]);
            }
        }
        #pragma unroll
        for (int ti = 0; ti < 4; ++ti)
            #pragma unroll
            for (int j = 0; j < 4; ++j) {
                int trow = m0 + wr * 64 + ti * 16 + hi * 4 + j;
                int wv = trow >> 6, n = trow & 63;
                int bb = wv / 1728; int rem = wv - bb * 1728;
                int dq = rem / 144; int rem2 = rem - dq * 144;
                int hq = rem2 / 12; int wq = rem2 - hq * 12;
                int l = (dq * 4 + (n >> 4)) * 2304 + (hq * 4 + ((n >> 2) & 3)) * 48 + (wq * 4 + (n & 3));
                long base = ((long)bb * L_TOT + l) * 192;
                #pragma unroll
                for (int tj = 0; tj < 2; ++tj) {
                    int col = nc * 64 + wc * 32 + tj * 16 + lo;
                    out1[base + col] = (bf16)(x[base + col] + acc[ti][tj][j] + bias[col]);
                }
            }
    }
}

// ---------------- fc1 GEMM: fragment-major A/B, transpose epilogue ----------------
__global__ __launch_bounds__(256) void gemm_fc1(
    const bf16* __restrict__ y, const bf16* __restrict__ wt,
    const float* __restrict__ bias, bf16* __restrict__ h_t) {
    __shared__ bf16 tl[64][136];
    int m0 = blockIdx.x * 128;
    int c0 = m0 >> 6;
    int wid = threadIdx.x >> 6, lane = threadIdx.x & 63;
    int wr = wid >> 1, wc = wid & 1;
    int lo = lane & 15, hi = lane >> 4;
    f32x4 zf = {0.f, 0.f, 0.f, 0.f};
    int bb = m0 / L_TOT; int l0 = m0 - bb * L_TOT;
    int col = threadIdx.x >> 2, seg = threadIdx.x & 3;

    const bf16* Ab = y + (long)(c0 + wr) * 12288 + (lo * 32 + hi * 8);
    bf16x8 a[4][6];
    #pragma unroll
    for (int ti = 0; ti < 4; ++ti)
        #pragma unroll
        for (int ks = 0; ks < 6; ++ks)
            a[ti][ks] = ld8(Ab + ks * 2048 + ti * 512);

    #pragma unroll
    for (int nc = 0; nc < 6; ++nc) {
        f32x4 acc[4][2];
        #pragma unroll
        for (int i = 0; i < 4; ++i) { acc[i][0] = zf; acc[i][1] = zf; }
        const bf16* Bb = wt + (long)nc * 12288 + (wc * 32 + lo) * 32 + hi * 8;
        #pragma unroll
        for (int ks = 0; ks < 6; ++ks) {
            bf16x8 b0 = ld8(Bb + ks * 2048);
            bf16x8 b1 = ld8(Bb + ks * 2048 + 512);
            #pragma unroll
            for (int ti = 0; ti < 4; ++ti) {
                acc[ti][0] = mfma16(a[ti][ks], b0, acc[ti][0]);
                acc[ti][1] = mfma16(a[ti][ks], b1, acc[ti][1]);
            }
        }
        if (nc) __syncthreads();
        #pragma unroll
        for (int ti = 0; ti < 4; ++ti)
            #pragma unroll
            for (int tj = 0; tj < 2; ++tj)
                #pragma unroll
                for (int j = 0; j < 4; ++j) {
                    int rl = wr * 64 + ti * 16 + hi * 4 + j;
                    int cl = wc * 32 + tj * 16 + lo;
                    tl[cl][rl] = (bf16)(acc[ti][tj][j] + bias[nc * 64 + cl]);
                }
        __syncthreads();
        bf16* dst = h_t + ((long)bb * 384 + nc * 64 + col) * L_TOT + l0 + seg * 32;
        #pragma unroll
        for (int i8 = 0; i8 < 4; ++i8)
            *(bf16x8*)(dst + i8 * 8) = *(const bf16x8*)(&tl[col][seg * 32 + i8 * 8]);
    }
}

// ---------------- depthwise conv 3^3 + BN + GELU (slab=4, stride-56 LDS, division-free staging) ----------------
__global__ __launch_bounds__(320) void dwconv_bn_gelu(
    const bf16* __restrict__ h_t, const float* __restrict__ wconv,
    const float* __restrict__ cb, const float* __restrict__ bng,
    const float* __restrict__ bnb, const float* __restrict__ bnm,
    const float* __restrict__ bnv, bf16* __restrict__ g_t) {
    // 1 guard row + 6*48 data rows, stride 56; cols 48..55 of every row are zero. 32368B -> 5 blocks/CU.
    __shared__ __align__(16) bf16 tile[289 * 56];
    int blk = blockIdx.x;
    int bb = blk / 4608; int rem = blk - bb * 4608;
    int ch = rem / 12; int zb = rem - ch * 12; int z0 = zb * 4;
    const bf16* src = h_t + ((long)bb * 384 + ch) * L_TOT;

    int y = threadIdx.x / 6, cx = threadIdx.x - y * 6, x0 = cx * 8;
    bool active = threadIdx.x < 288;

    // zero guard cells: guard row (7 uint4) + right columns (48..55) of 288 data rows
    uint4 zv = make_uint4(0u, 0u, 0u, 0u);
    for (int i = threadIdx.x; i < 295; i += 320) {
        int e = (i < 7) ? i * 8 : ((i - 7 + 1) * 56 + 48);
        *(uint4*)(tile + e) = zv;
    }
    // stage 6 planes x 48 rows x 48 cols, division-free (thread's own (y,cx)), 16B-aligned writes
    if (active) {
        #pragma unroll
        for (int zi = 0; zi < 6; ++zi) {
            int gz = z0 - 1 + zi;
            uint4 val = zv;
            if (gz >= 0 && gz < 48) val = *(const uint4*)(src + (long)gz * 2304 + y * 48 + x0);
            *(uint4*)(tile + (1 + zi * 48 + y) * 56 + x0) = val;
        }
    }
    float wgt[27];
    #pragma unroll
    for (int i = 0; i < 27; ++i) wgt[i] = wconv[ch * 27 + i];
    float scale = bng[ch] * rsqrtf(bnv[ch] + 1e-5f);
    float shift = bnb[ch] - bnm[ch] * scale;
    float cbias = cb[ch];
    __syncthreads();

    if (active) {
        __builtin_assume(y < 48);
        bool up_ok = (y > 0), dn_ok = (y < 47);
        bf16* dstc = g_t + ((long)bb * 384 + ch) * L_TOT + (long)z0 * 2304 + y * 48 + x0;
        float acc[4][8];
        #pragma unroll
        for (int p = 0; p < 4; ++p)
            #pragma unroll
            for (int k = 0; k < 8; ++k) acc[p][k] = 0.f;

        #pragma unroll
        for (int zi = 0; zi < 6; ++zi) {
            const bf16* plane = tile + (1 + zi * 48) * 56;
            #pragma unroll
            for (int dy = 0; dy < 3; ++dy) {
                bool ok = (dy == 1) || (dy == 0 ? up_ok : dn_ok);
                if (ok) {
                    const bf16* rp = plane + (y + dy - 1) * 56 + x0;
                    bf16x8 mv = ld8(rp);            // single ds_read_b128 (16B aligned)
                    float s[10];
                    s[0] = (float)rp[-1];           // cx==0 -> prev row col 55 == 0
                    #pragma unroll
                    for (int i = 0; i < 8; ++i) s[i + 1] = (float)mv[i];
                    s[9] = (float)rp[8];            // cx==5 -> col 48 == 0
                    #pragma unroll
                    for (int dz = 0; dz < 3; ++dz) {
                        int p = zi - dz;
                        if (p >= 0 && p <= 3) {     // compile-time after unroll
                            float w0 = wgt[dz * 9 + dy * 3 + 0];
                            float w1 = wgt[dz * 9 + dy * 3 + 1];
                            float w2 = wgt[dz * 9 + dy * 3 + 2];
                            #pragma unroll
                            for (int k = 0; k < 8; ++k)
                                acc[p][k] = fmaf(w0, s[k], fmaf(w1, s[k + 1], fmaf(w2, s[k + 2], acc[p][k])));
                        }
                    }
                }
            }
            if (zi >= 2) {
                int p = zi - 2;
                bf16x8 ov;
                #pragma unroll
                for (int k = 0; k < 8; ++k) {
                    float v = acc[p][k] + cbias;
                    v = fmaf(v, scale, shift);
                    // GELU tanh form via exp2 (log2e folded): v - v/(2^(u2) + 1)
                    float v2 = v * v;
                    float u2 = v * fmaf(v2, 0.10294357f, 2.3022080918f);
                    float e  = exp2f(u2);
                    float q  = __builtin_amdgcn_rcpf(e + 1.0f);
                    ov[k] = (bf16)(v - v * q);
                }
                *(bf16x8*)(dstc + p * 2304) = ov;
            }
        }
    }
}

// ---------------- fc2 GEMM: M=64, 2-deep prefetch, early residual preload ----------------
__global__ __launch_bounds__(256) void gemm_fc2(
    const bf16* __restrict__ g_t, const bf16* __restrict__ wt,
    const float* __restrict__ bias, const bf16* __restrict__ out1,
    float* __restrict__ out) {
    __shared__ bf16 As[2][4096];        // [64 tok][64 ch], elem = tok*64 + (ch ^ (S(tok)<<3))
    int m0 = blockIdx.x * 64;
    int wc = threadIdx.x >> 6, lane = threadIdx.x & 63;
    int lo = lane & 15, hi = lane >> 4;
    int bb = m0 / L_TOT, l0 = m0 - bb * L_TOT;
    f32x4 zf = {0.f, 0.f, 0.f, 0.f};
    f32x4 acc[3][4];                    // [tj][ti]
    #pragma unroll
    for (int tj = 0; tj < 3; ++tj)
        #pragma unroll
        for (int ti = 0; ti < 4; ++ti) acc[tj][ti] = zf;

    int sch = threadIdx.x >> 3;          // channel within pass (0..31)
    int seg = threadIdx.x & 7;           // 8-token segment
    const bf16* srcb = g_t + ((long)bb * 384 + sch) * L_TOT + l0 + seg * 8;

    bf16x8 r[2][2];
    // tile 0 -> As[0]
    #pragma unroll
    for (int p = 0; p < 2; ++p) r[0][p] = ld8(srcb + (long)(p * 32) * L_TOT);
    #pragma unroll
    for (int p = 0; p < 2; ++p)
        #pragma unroll
        for (int i = 0; i < 8; ++i)
            As[0][(seg * 8 + i) * 64 + ((p * 32 + sch) ^ (((seg ^ i) & 7) << 3))] = r[0][p][i];
    // 2-deep prefetch: tiles 1 and 2
    #pragma unroll
    for (int p = 0; p < 2; ++p) r[0][p] = ld8(srcb + (long)(64 + p * 32) * L_TOT);
    #pragma unroll
    for (int p = 0; p < 2; ++p) r[1][p] = ld8(srcb + (long)(128 + p * 32) * L_TOT);

    // early residual preload (overlaps the whole GEMM)
    float res[3][4][4];
    #pragma unroll
    for (int tj = 0; tj < 3; ++tj)
        #pragma unroll
        for (int ti = 0; ti < 4; ++ti)
            #pragma unroll
            for (int j = 0; j < 4; ++j) {
                long trow = m0 + ti * 16 + hi * 4 + j;
                res[tj][ti][j] = (float)out1[trow * 192 + wc * 48 + tj * 16 + lo];
            }
    __syncthreads();

    #pragma unroll
    for (int t = 0; t < 6; ++t) {
        const bf16* Ac = As[t & 1];
        #pragma unroll
        for (int ksin = 0; ksin < 2; ++ksin) {
            bf16x8 a[4];
            #pragma unroll
            for (int ti = 0; ti < 4; ++ti) {
                int rr = ti * 16 + lo;
                int S = ((rr >> 3) ^ rr) & 7;
                a[ti] = *(const bf16x8*)&Ac[rr * 64 + ((ksin * 32 + hi * 8) ^ (S << 3))];
            }
            #pragma unroll
            for (int tj = 0; tj < 3; ++tj) {
                int cstart = wc * 48 + tj * 16;
                bf16x8 b0 = ld8(wt + ((long)((cstart >> 6) * 12 + t * 2 + ksin) * 64 + (cstart & 63) + lo) * 32 + hi * 8);
                #pragma unroll
                for (int ti = 0; ti < 4; ++ti)
                    acc[tj][ti] = mfma16(a[ti], b0, acc[tj][ti]);
            }
        }
        if (t < 5) {
            bf16* An = As[(t + 1) & 1];
            #pragma unroll
            for (int p = 0; p < 2; ++p)
                #pragma unroll
                for (int i = 0; i < 8; ++i)
                    An[(seg * 8 + i) * 64 + ((p * 32 + sch) ^ (((seg ^ i) & 7) << 3))] = r[t & 1][p][i];
        }
        if (t < 3) {
            #pragma unroll
            for (int p = 0; p < 2; ++p)
                r[t & 1][p] = ld8(srcb + (long)((t + 3) * 64 + p * 32) * L_TOT);
        }
        __syncthreads();
    }
    #pragma unroll
    for (int tj = 0; tj < 3; ++tj)
        #pragma unroll
        for (int ti = 0; ti < 4; ++ti)
            #pragma unroll
            for (int j = 0; j < 4; ++j) {
                long trow = m0 + ti * 16 + hi * 4 + j;
                int col = wc * 48 + tj * 16 + lo;
                out[trow * 192 + col] = res[tj][ti][j] + acc[tj][ti][j] + bias[col];
            }
}

// ---------------- host ----------------
extern "C" void kernel_launch(void* const* d_in, const int* in_sizes, int n_in,
                              void* d_out, int out_size, void* d_ws, size_t ws_size,
                              hipStream_t stream) {
    (void)in_sizes; (void)n_in; (void)out_size; (void)ws_size;
    const float* x     = (const float*)d_in[0];
    const float* ln1g  = (const float*)d_in[4];
    const float* ln1b  = (const float*)d_in[5];
    const float* ln2g  = (const float*)d_in[6];
    const float* ln2b  = (const float*)d_in[7];
    const float* qkvw  = (const float*)d_in[8];
    const float* qkvb  = (const float*)d_in[9];
    const float* rpb   = (const float*)d_in[10];
    const float* projw = (const float*)d_in[11];
    const float* projb = (const float*)d_in[12];
    const float* fc1w  = (const float*)d_in[13];
    const float* fc1b  = (const float*)d_in[14];
    const float* dww   = (const float*)d_in[15];
    const float* dwb   = (const float*)d_in[16];
    const float* bng   = (const float*)d_in[17];
    const float* bnb   = (const float*)d_in[18];
    const float* bnm   = (const float*)d_in[19];
    const float* bnv   = (const float*)d_in[20];
    const float* fc2w  = (const float*)d_in[21];
    const float* fc2b  = (const float*)d_in[22];
    float* out = (float*)d_out;

    char* ws = (char*)d_ws;
    size_t o = 0;
    bf16*  out1 = (bf16*)(ws + o);                           // bf16 [2][L][192] = 85MB
    bf16*  vt_buf = (bf16*)(ws + o + 84934656); o += 169869312;  // vt in 2nd half (disjoint)
    bf16*  h_t  = (bf16*)(ws + o); o += 169869312;           // bf16 [2][384][L] (doubles as q|k before fc1)
    bf16*  region1 = (bf16*)(ws + o); o += 169869312;        // xw|aw -> y -> g_t
    bf16*  xw  = region1;
    bf16*  aw  = region1 + 42467328;
    bf16*  yb  = region1;
    bf16*  g_t = region1;
    bf16*  qkvwt  = (bf16*)(ws + o); o += 221184;
    bf16*  projwt = (bf16*)(ws + o); o += 73728;
    bf16*  fc1wt  = (bf16*)(ws + o); o += 147456;
    bf16*  fc2wt  = (bf16*)(ws + o); o += 147456;
    float* bias6  = (float*)(ws + o); o += 98304;

    bf16* q_buf  = h_t;
    bf16* k_buf  = h_t + 42467328;

    setup_all<<<1248, 256, 0, stream>>>(qkvw, projw, fc1w, fc2w, rpb,
                                        qkvwt, projwt, fc1wt, fc2wt, bias6);

    ln1_window<<<55296, 256, 0, stream>>>(x, ln1g, ln1b, xw);
    gemm_qkv<<<1728, 256, 0, stream>>>(xw, qkvwt, qkvb, q_buf, k_buf, vt_buf);
    attn_light<<<NWIN, 384, 0, stream>>>(q_buf, k_buf, vt_buf, bias6, aw);
    gemm_proj<<<1728, 256, 0, stream>>>(aw, projwt, projb, x, out1);
    ln2_kernel<<<55296, 256, 0, stream>>>(out1, ln2g, ln2b, yb);
    gemm_fc1<<<1728, 256, 0, stream>>>(yb, fc1wt, fc1b, h_t);
    dwconv_bn_gelu<<<9216, 320, 0, stream>>>(h_t, dww, dwb, bng, bnb, bnm, bnv, g_t);
    gemm_fc2<<<3456, 256, 0, stream>>>(g_t, fc2wt, fc2b, out1, out);
}